// Round 4
// baseline (8628.594 us; speedup 1.0000x reference)
//
#include <hip/hip_runtime.h>

// Problem constants: B=64, T=1024, I=512, H=1024, fp32 in/out.
#define B_  64
#define T_  1024
#define I_  512
#define H_  1024

typedef short short8 __attribute__((ext_vector_type(8)));
typedef float f32x4  __attribute__((ext_vector_type(4)));
typedef unsigned int u32x4 __attribute__((ext_vector_type(4)));
typedef unsigned long long u64;

__device__ __forceinline__ unsigned short f2bf(float f) {
    unsigned int u = __float_as_uint(f);
    unsigned int r = u + 0x7fffu + ((u >> 16) & 1u);   // RNE
    return (unsigned short)(r >> 16);
}
__device__ __forceinline__ float bf2f(unsigned short s) {
    return __uint_as_float(((unsigned int)s) << 16);
}

// Agent-scope cache-bypassing 16B load (coherent at MALL). Atomicity is NOT
// needed: the flag protocol guarantees data is fully published before read.
__device__ __forceinline__ u32x4 load_b128_agent(const void* p) {
    u32x4 r;
    asm volatile("global_load_dwordx4 %0, %1, off sc1"
                 : "=v"(r) : "v"(p) : "memory");
    return r;
}

// ---------------------------------------------------------------------------
// Kernel 1: xp = x @ input_w + b   ([65536,512] @ [512,1024] -> d_out)
// fp32 SGEMM, 128x128 tile, 256 threads, 8x8 per thread, BK=8. (unchanged)
// ---------------------------------------------------------------------------
#define BM 128
#define BN 128
#define BK 8

__global__ __launch_bounds__(256) void proj_kernel(
    const float* __restrict__ x, const float* __restrict__ w,
    const float* __restrict__ bias, float* __restrict__ out)
{
    __shared__ float As[BK][BM];
    __shared__ float Bs[BK][BN];

    const int tid = threadIdx.x;
    const int m0 = blockIdx.y * BM;
    const int n0 = blockIdx.x * BN;
    const int tx = tid & 15;
    const int ty = tid >> 4;

    const int arow = tid >> 1;
    const int acol = (tid & 1) * 4;
    const int brow = tid >> 5;
    const int bcol = (tid & 31) * 4;

    float acc[2][4][2][4];
    #pragma unroll
    for (int a = 0; a < 2; a++)
        #pragma unroll
        for (int b = 0; b < 4; b++)
            #pragma unroll
            for (int c = 0; c < 2; c++)
                #pragma unroll
                for (int d = 0; d < 4; d++) acc[a][b][c][d] = 0.f;

    for (int k0 = 0; k0 < I_; k0 += BK) {
        float4 av = *(const float4*)&x[(size_t)(m0 + arow) * I_ + k0 + acol];
        float4 bv = *(const float4*)&w[(size_t)(k0 + brow) * H_ + n0 + bcol];
        __syncthreads();
        As[acol + 0][arow] = av.x;
        As[acol + 1][arow] = av.y;
        As[acol + 2][arow] = av.z;
        As[acol + 3][arow] = av.w;
        *(float4*)&Bs[brow][bcol] = bv;
        __syncthreads();
        #pragma unroll
        for (int kk = 0; kk < BK; kk++) {
            float4 a0 = *(const float4*)&As[kk][ty * 4];
            float4 a1 = *(const float4*)&As[kk][64 + ty * 4];
            float4 b0 = *(const float4*)&Bs[kk][tx * 4];
            float4 b1 = *(const float4*)&Bs[kk][64 + tx * 4];
            const float am[2][4] = {{a0.x,a0.y,a0.z,a0.w},{a1.x,a1.y,a1.z,a1.w}};
            const float bn[2][4] = {{b0.x,b0.y,b0.z,b0.w},{b1.x,b1.y,b1.z,b1.w}};
            #pragma unroll
            for (int mb = 0; mb < 2; mb++)
                #pragma unroll
                for (int mr = 0; mr < 4; mr++)
                    #pragma unroll
                    for (int nb = 0; nb < 2; nb++)
                        #pragma unroll
                        for (int nr = 0; nr < 4; nr++)
                            acc[mb][mr][nb][nr] += am[mb][mr] * bn[nb][nr];
        }
    }

    float4 bias0 = *(const float4*)&bias[n0 + tx * 4];
    float4 bias1 = *(const float4*)&bias[n0 + 64 + tx * 4];
    const float bb[2][4] = {{bias0.x,bias0.y,bias0.z,bias0.w},
                            {bias1.x,bias1.y,bias1.z,bias1.w}};
    #pragma unroll
    for (int mb = 0; mb < 2; mb++)
        #pragma unroll
        for (int mr = 0; mr < 4; mr++) {
            int m = m0 + mb * 64 + ty * 4 + mr;
            #pragma unroll
            for (int nb = 0; nb < 2; nb++) {
                float4 v;
                v.x = acc[mb][mr][nb][0] + bb[nb][0];
                v.y = acc[mb][mr][nb][1] + bb[nb][1];
                v.z = acc[mb][mr][nb][2] + bb[nb][2];
                v.w = acc[mb][mr][nb][3] + bb[nb][3];
                *(float4*)&out[(size_t)m * H_ + n0 + nb * 64 + tx * 4] = v;
            }
        }
}

// ---------------------------------------------------------------------------
// Kernel 2: sequential scan, per-wave flag protocol + swizzled h exchange.
//
// Round-4 changes vs round-2 (the 7.32 ms config; round-3's agent fence is
// reverted):
//  1. PFD 8 -> 16: 32 dwordx4 in flight per wave, halving the serialized
//     latency of the h-load stream if it is pipeline-depth-bound.
//  2. O-invariant counted vmcnt ladder. At the wait before consuming chunk
//     kc, the guarantee "chunk kc's 2 loads retired" needs outstanding <=
//     (#h-loads issued after them) -- independent of how many older non-h
//     vmem ops (flag store, out stores, pre-poll, nxv, poll loads) exist,
//     because vmcnt retires strictly in issue order:
//       kc <16      : issued-after = 30 -> vmcnt(30)
//       kc in[16,22): issued-after <= 62-2kc (>=18 at kc=21) -> vmcnt(18)
//       kc >=22     : all 64 issued long ago -> vmcnt(0)
//  3. Speculative flag pre-poll: issue a relaxed flags load at the END of
//     step t (after the flag store); use it as the first poll check at
//     t+1. When partners are ahead, the poll loop is skipped entirely.
//
// hbuf swizzle (unchanged): u32 idx =
//   ((par*4 + plane)*32 + kc)*512 + half*256 + lane*4 + i4
// lane = quad*16 + (b&15), k = kc*32 + quad*8 + half*4 + i4.
// Producer: 4 sc1 dword stores + vmcnt(0) + flags[plane][wg] = t+1.
//
// MFMA 16x16x32_bf16: A: m=lane&15,k=quad*8+i  B: n=lane&15,k=quad*8+i
//                     C/D: col=lane&15, row=quad*4+reg  (HW-verified earlier)
// 3 independent accumulators break the 96-deep dependent MFMA chain.
// ---------------------------------------------------------------------------
#define PFD 16  // prefetch depth in 32-k chunks; 16*2 = 32 dwordx4 in flight

__global__ __launch_bounds__(256, 1) void scan_kernel(
    const float* __restrict__ W,        // hidden_w [H][H]
    float* __restrict__ out,            // d_out: xp on entry, h on exit
    unsigned int* __restrict__ hbuf,    // ws: swizzled [2][4][32][2][64][4] u32
    int* __restrict__ flags)            // ws: [4 plane][64 wg] ints, pre-zeroed
{
    __shared__ short8 wlds[32][64];     // lo-part B-fragments, 32 KB

    const int wg   = blockIdx.x;        // 0..63 -> columns [wg*16, wg*16+16)
    const int tid  = threadIdx.x;
    const int wave = tid >> 6;          // plane: batches [wave*16, wave*16+16)
    const int lane = tid & 63;
    const int quad = lane >> 4;
    const int l16  = lane & 15;
    const int jbase = wg * 16;
    const int b0    = wave * 16;
    const int j     = jbase + l16;

    // ---- preload W slice: wh -> regs (all kc), wl -> LDS (my 8 kc) ----
    short8 wh[32];
    #pragma unroll
    for (int kc = 0; kc < 32; kc++) {
        short8 wlv;
        #pragma unroll
        for (int i = 0; i < 8; i++) {
            float wv = W[(size_t)(kc * 32 + quad * 8 + i) * H_ + j];
            unsigned short hi = f2bf(wv);
            wh[kc][i] = (short)hi;
            wlv[i] = (short)f2bf(wv - bf2f(hi));
        }
        if ((kc >> 3) == wave) wlds[kc][lane] = wlv;
    }
    __syncthreads();    // only for the W-LDS fill; none in the t-loop

    const size_t TH = (size_t)T_ * H_;
    size_t oidx[4];
    float xv[4];
    #pragma unroll
    for (int r = 0; r < 4; r++) {
        int b = b0 + quad * 4 + r;
        oidx[r] = (size_t)b * TH + j;      // (b, t=0, j)
        xv[r] = out[oidx[r]];
    }

    // consumer: byte base of my (plane, lane) within parity-0 region
    const char* hb_base = (const char*)hbuf + (size_t)wave * 65536
                        + (size_t)lane * 16;
    // producer: u32 base (parity-0) for my (j, quad) slot; element r at +r*4
    const int pbase = ((j >> 5) << 9) + (((j >> 2) & 1) << 8)
                    + ((j >> 3) & 3) * 64 + quad * 16 + (j & 3);
    unsigned int* pb_base = hbuf + (size_t)wave * 16384 + pbase;

    int* flagp = flags + wave * 64;      // my plane's flags; I publish [wg]

    int pfl = 0;                         // speculative pre-polled flag value

    for (int t = 0; t < T_; t++) {
        // prefetch next step's xp early (plain cached loads, wg-private data)
        float nxv[4] = {0.f, 0.f, 0.f, 0.f};
        if (t + 1 < T_) {
            #pragma unroll
            for (int r = 0; r < 4; r++) nxv[r] = out[oidx[r] + H_];
        }

        f32x4 a0 = {0.f,0.f,0.f,0.f}, a1 = {0.f,0.f,0.f,0.f},
              a2 = {0.f,0.f,0.f,0.f};
        if (t > 0) {
            // wait until every wg's plane-`wave` producer published h_{t-1};
            // first check uses the pre-polled value from last iteration.
            int v = pfl;
            while (!__all(v >= t)) {
                v = __hip_atomic_load(&flagp[lane], __ATOMIC_RELAXED,
                                      __HIP_MEMORY_SCOPE_AGENT);
            }
            // cheap wg-scope fence: compiler barrier, no cache maintenance
            __builtin_amdgcn_fence(__ATOMIC_ACQUIRE, "workgroup");

            const char* hb = hb_base + (size_t)((t - 1) & 1) * 262144;

            u32x4 buf[PFD][2];
            #pragma unroll
            for (int d = 0; d < PFD; d++) {
                buf[d][0] = load_b128_agent(hb + d * 2048);
                buf[d][1] = load_b128_agent(hb + d * 2048 + 1024);
            }

            #pragma unroll
            for (int kc = 0; kc < 32; kc++) {
                if (kc < 16) {
                    asm volatile("s_waitcnt vmcnt(30)" ::: "memory");
                } else if (kc < 22) {
                    asm volatile("s_waitcnt vmcnt(18)" ::: "memory");
                } else if (kc == 22) {
                    asm volatile("s_waitcnt vmcnt(0)" ::: "memory");
                }
                __builtin_amdgcn_sched_barrier(0);

                u32x4 c0 = buf[kc & (PFD - 1)][0];
                u32x4 c1 = buf[kc & (PFD - 1)][1];
                short8 ah, al;
                #pragma unroll
                for (int i = 0; i < 4; i++) {
                    ah[i]     = (short)(c0[i] >> 16);
                    al[i]     = (short)(c0[i] & 0xffffu);
                    ah[4 + i] = (short)(c1[i] >> 16);
                    al[4 + i] = (short)(c1[i] & 0xffffu);
                }
                short8 wlv = wlds[kc][lane];
                a0 = __builtin_amdgcn_mfma_f32_16x16x32_bf16(ah, wh[kc], a0, 0, 0, 0);
                a1 = __builtin_amdgcn_mfma_f32_16x16x32_bf16(ah, wlv,    a1, 0, 0, 0);
                a2 = __builtin_amdgcn_mfma_f32_16x16x32_bf16(al, wh[kc], a2, 0, 0, 0);

                if (kc + PFD < 32) {
                    buf[kc & (PFD - 1)][0] =
                        load_b128_agent(hb + (kc + PFD) * 2048);
                    buf[kc & (PFD - 1)][1] =
                        load_b128_agent(hb + (kc + PFD) * 2048 + 1024);
                }
            }
        }

        // epilogue: h = tanh(acc + xp); publish swizzled u32s, then flag
        float hv[4];
        #pragma unroll
        for (int r = 0; r < 4; r++)
            hv[r] = tanhf(a0[r] + a1[r] + a2[r] + xv[r]);

        if (t + 1 < T_) {
            unsigned int* pb = pb_base + (size_t)(t & 1) * 65536;
            #pragma unroll
            for (int r = 0; r < 4; r++) {
                unsigned short hi = f2bf(hv[r]);
                unsigned short lo = f2bf(hv[r] - bf2f(hi));
                unsigned int pk = ((unsigned int)hi << 16) | (unsigned int)lo;
                __hip_atomic_store(&pb[r * 4], pk, __ATOMIC_RELAXED,
                                   __HIP_MEMORY_SCOPE_AGENT);
            }
            asm volatile("s_waitcnt vmcnt(0)" ::: "memory");
            if (lane == 0)
                __hip_atomic_store(&flagp[wg], t + 1, __ATOMIC_RELAXED,
                                   __HIP_MEMORY_SCOPE_AGENT);
            // speculative pre-poll for next step's wait (fire-and-forget)
            pfl = __hip_atomic_load(&flagp[lane], __ATOMIC_RELAXED,
                                    __HIP_MEMORY_SCOPE_AGENT);
        }

        // off critical path: fp32 h store to d_out (wg-private addresses)
        #pragma unroll
        for (int r = 0; r < 4; r++) {
            out[oidx[r]] = hv[r];
            oidx[r] += H_;
            xv[r] = nxv[r];
        }
    }
}

// ---------------------------------------------------------------------------
extern "C" void kernel_launch(void* const* d_in, const int* in_sizes, int n_in,
                              void* d_out, int out_size, void* d_ws, size_t ws_size,
                              hipStream_t stream) {
    const float* x        = (const float*)d_in[0];  // [B,T,I]
    const float* hidden_w = (const float*)d_in[1];  // [H,H]
    const float* input_w  = (const float*)d_in[2];  // [I,H]
    const float* bias     = (const float*)d_in[3];  // [H]
    float* out = (float*)d_out;                     // [B,T,H]

    // ws layout: hbuf swizzled [2][4][32][2][64][4] u32 = 512 KiB, then flags
    unsigned int* hbuf = (unsigned int*)d_ws;
    int* flags = (int*)((char*)d_ws + (size_t)512 * 1024);

    hipMemsetAsync(flags, 0, 4 * 64 * sizeof(int), stream);

    dim3 pgrid(H_ / BN, (B_ * T_) / BM);   // (8, 512)
    proj_kernel<<<pgrid, 256, 0, stream>>>(x, input_w, bias, out);
    scan_kernel<<<64, 256, 0, stream>>>(hidden_w, out, hbuf, flags);
}

// Round 6
// 7930.510 us; speedup vs baseline: 1.0880x; 1.0880x over previous
//
#include <hip/hip_runtime.h>

// Problem constants: B=64, T=1024, I=512, H=1024, fp32 in/out.
#define B_  64
#define T_  1024
#define I_  512
#define H_  1024

typedef short short8 __attribute__((ext_vector_type(8)));
typedef float f32x4  __attribute__((ext_vector_type(4)));
typedef unsigned int u32x4 __attribute__((ext_vector_type(4)));
typedef unsigned long long u64;

__device__ __forceinline__ unsigned short f2bf(float f) {
    unsigned int u = __float_as_uint(f);
    unsigned int r = u + 0x7fffu + ((u >> 16) & 1u);   // RNE
    return (unsigned short)(r >> 16);
}
__device__ __forceinline__ float bf2f(unsigned short s) {
    return __uint_as_float(((unsigned int)s) << 16);
}

// Agent-scope cache-bypassing 16B load (coherent at MALL). Atomicity is NOT
// needed: the flag protocol guarantees data is fully published before read.
__device__ __forceinline__ u32x4 load_b128_agent(const void* p) {
    u32x4 r;
    asm volatile("global_load_dwordx4 %0, %1, off sc1"
                 : "=v"(r) : "v"(p) : "memory");
    return r;
}

// ---------------------------------------------------------------------------
// Kernel 1: xp = x @ input_w + b   ([65536,512] @ [512,1024] -> d_out)
// fp32 SGEMM, 128x128 tile, 256 threads, 8x8 per thread, BK=8. (unchanged)
// ---------------------------------------------------------------------------
#define BM 128
#define BN 128
#define BK 8

__global__ __launch_bounds__(256) void proj_kernel(
    const float* __restrict__ x, const float* __restrict__ w,
    const float* __restrict__ bias, float* __restrict__ out)
{
    __shared__ float As[BK][BM];
    __shared__ float Bs[BK][BN];

    const int tid = threadIdx.x;
    const int m0 = blockIdx.y * BM;
    const int n0 = blockIdx.x * BN;
    const int tx = tid & 15;
    const int ty = tid >> 4;

    const int arow = tid >> 1;
    const int acol = (tid & 1) * 4;
    const int brow = tid >> 5;
    const int bcol = (tid & 31) * 4;

    float acc[2][4][2][4];
    #pragma unroll
    for (int a = 0; a < 2; a++)
        #pragma unroll
        for (int b = 0; b < 4; b++)
            #pragma unroll
            for (int c = 0; c < 2; c++)
                #pragma unroll
                for (int d = 0; d < 4; d++) acc[a][b][c][d] = 0.f;

    for (int k0 = 0; k0 < I_; k0 += BK) {
        float4 av = *(const float4*)&x[(size_t)(m0 + arow) * I_ + k0 + acol];
        float4 bv = *(const float4*)&w[(size_t)(k0 + brow) * H_ + n0 + bcol];
        __syncthreads();
        As[acol + 0][arow] = av.x;
        As[acol + 1][arow] = av.y;
        As[acol + 2][arow] = av.z;
        As[acol + 3][arow] = av.w;
        *(float4*)&Bs[brow][bcol] = bv;
        __syncthreads();
        #pragma unroll
        for (int kk = 0; kk < BK; kk++) {
            float4 a0 = *(const float4*)&As[kk][ty * 4];
            float4 a1 = *(const float4*)&As[kk][64 + ty * 4];
            float4 b0 = *(const float4*)&Bs[kk][tx * 4];
            float4 b1 = *(const float4*)&Bs[kk][64 + tx * 4];
            const float am[2][4] = {{a0.x,a0.y,a0.z,a0.w},{a1.x,a1.y,a1.z,a1.w}};
            const float bn[2][4] = {{b0.x,b0.y,b0.z,b0.w},{b1.x,b1.y,b1.z,b1.w}};
            #pragma unroll
            for (int mb = 0; mb < 2; mb++)
                #pragma unroll
                for (int mr = 0; mr < 4; mr++)
                    #pragma unroll
                    for (int nb = 0; nb < 2; nb++)
                        #pragma unroll
                        for (int nr = 0; nr < 4; nr++)
                            acc[mb][mr][nb][nr] += am[mb][mr] * bn[nb][nr];
        }
    }

    float4 bias0 = *(const float4*)&bias[n0 + tx * 4];
    float4 bias1 = *(const float4*)&bias[n0 + 64 + tx * 4];
    const float bb[2][4] = {{bias0.x,bias0.y,bias0.z,bias0.w},
                            {bias1.x,bias1.y,bias1.z,bias1.w}};
    #pragma unroll
    for (int mb = 0; mb < 2; mb++)
        #pragma unroll
        for (int mr = 0; mr < 4; mr++) {
            int m = m0 + mb * 64 + ty * 4 + mr;
            #pragma unroll
            for (int nb = 0; nb < 2; nb++) {
                float4 v;
                v.x = acc[mb][mr][nb][0] + bb[nb][0];
                v.y = acc[mb][mr][nb][1] + bb[nb][1];
                v.z = acc[mb][mr][nb][2] + bb[nb][2];
                v.w = acc[mb][mr][nb][3] + bb[nb][3];
                *(float4*)&out[(size_t)m * H_ + n0 + nb * 64 + tx * 4] = v;
            }
        }
}

// ---------------------------------------------------------------------------
// Kernel 2: sequential scan, per-wave flag protocol + swizzled h exchange.
//
// Round-6 = round-5 resubmission (infra failure, no data; source re-audited):
// HALVE THE CONSUMER WAVE COUNT. Fabric read volume per step is
// (#waves x 64 KB plane-slice) regardless of columns-per-wave, and r3/r4
// established the load stream is MALL-volume/queue-bound, not depth-bound.
// 32 wgs x 256 threads; each wave owns 32 columns (two 16-col groups):
// 128 waves -> 8 MB/step instead of 16. Per chunk: same 2 h-loads, unpack
// once, 2x (hi,lo) LDS reads, 6 MFMAs into 6 accumulators. The whole W slice
// (hi+lo for 32 cols = 128 KB) lives in static LDS (gfx950 allows 160 KB;
// the 8-phase GEMM template verified 128 KB static). Everything else is the
// proven round-2 config: PFD=8, workgroup-scope fence, sc1 loads/stores,
// vmcnt{14,0} ladder + sched_barrier(0) (guide rule #18). s_sleep(1) is
// restored in the poll loop (hardening; proven in the 18.9 ms baseline).
//
// hbuf swizzle (unchanged): u32 idx =
//   ((par*4 + plane)*32 + kc)*512 + half*256 + lane*4 + i4
// lane = quad*16 + (b&15), k = kc*32 + quad*8 + half*4 + i4.  (k == producer j)
// Producer: 8 sc1 dword stores (2 groups x 4 rows) + vmcnt(0) + flag.
//
// MFMA 16x16x32_bf16: A: m=lane&15,k=quad*8+i  B: n=lane&15,k=quad*8+i
//                     C/D: col=lane&15, row=quad*4+reg  (HW-verified earlier)
// ---------------------------------------------------------------------------
#define PFD 8   // prefetch depth in 32-k chunks; 8*2 = 16 dwordx4 in flight
#define NWG 32  // scan workgroups; each owns 32 columns

__global__ __launch_bounds__(256, 1) void scan_kernel(
    const float* __restrict__ W,        // hidden_w [H][H]
    float* __restrict__ out,            // d_out: xp on entry, h on exit
    unsigned int* __restrict__ hbuf,    // ws: swizzled [2][4][32][2][64][4] u32
    int* __restrict__ flags)            // ws: [4 plane][NWG] ints, pre-zeroed
{
    __shared__ short8 whds[2][32][64];  // hi-part B-fragments, 2 groups, 64 KB
    __shared__ short8 wlds[2][32][64];  // lo-part B-fragments, 2 groups, 64 KB

    const int wg   = blockIdx.x;        // 0..31 -> columns [wg*32, wg*32+32)
    const int tid  = threadIdx.x;
    const int wave = tid >> 6;          // plane: batches [wave*16, wave*16+16)
    const int lane = tid & 63;
    const int quad = lane >> 4;
    const int l16  = lane & 15;
    const int jbase = wg * 32;
    const int b0    = wave * 16;

    // ---- preload W slice into LDS: each wave fills its 8 kc x 2 groups ----
    #pragma unroll
    for (int kc = 0; kc < 32; kc++) {
        if ((kc >> 3) == wave) {
            #pragma unroll
            for (int g = 0; g < 2; g++) {
                const int j = jbase + g * 16 + l16;
                short8 whv, wlv;
                #pragma unroll
                for (int i = 0; i < 8; i++) {
                    float wv = W[(size_t)(kc * 32 + quad * 8 + i) * H_ + j];
                    unsigned short hi = f2bf(wv);
                    whv[i] = (short)hi;
                    wlv[i] = (short)f2bf(wv - bf2f(hi));
                }
                whds[g][kc][lane] = whv;
                wlds[g][kc][lane] = wlv;
            }
        }
    }
    __syncthreads();    // only for the W-LDS fill; none in the t-loop

    const size_t TH = (size_t)T_ * H_;
    size_t oidx[4];
    float xv[2][4];
    #pragma unroll
    for (int r = 0; r < 4; r++) {
        int b = b0 + quad * 4 + r;
        oidx[r] = (size_t)b * TH + jbase + l16;   // (b, t=0, group-0 col)
        xv[0][r] = out[oidx[r]];
        xv[1][r] = out[oidx[r] + 16];
    }

    // consumer: byte base of my (plane, lane) within parity-0 region
    const char* hb_base = (const char*)hbuf + (size_t)wave * 65536
                        + (size_t)lane * 16;
    // producer: u32 bases (parity-0) for my (j, quad) slots; element r at +r*4
    unsigned int* pb_base[2];
    #pragma unroll
    for (int g = 0; g < 2; g++) {
        const int pj = jbase + g * 16 + l16;
        const int pbase = ((pj >> 5) << 9) + (((pj >> 2) & 1) << 8)
                        + ((pj >> 3) & 3) * 64 + quad * 16 + (pj & 3);
        pb_base[g] = hbuf + (size_t)wave * 16384 + pbase;
    }

    int* flagp = flags + wave * NWG;     // my plane's flags; I publish [wg]

    for (int t = 0; t < T_; t++) {
        // prefetch next step's xp early (plain cached loads, wg-private data)
        float nxv[2][4] = {{0.f,0.f,0.f,0.f},{0.f,0.f,0.f,0.f}};
        if (t + 1 < T_) {
            #pragma unroll
            for (int r = 0; r < 4; r++) {
                nxv[0][r] = out[oidx[r] + H_];
                nxv[1][r] = out[oidx[r] + H_ + 16];
            }
        }

        f32x4 acc[2][3];
        #pragma unroll
        for (int g = 0; g < 2; g++)
            #pragma unroll
            for (int s = 0; s < 3; s++)
                acc[g][s] = (f32x4){0.f, 0.f, 0.f, 0.f};

        if (t > 0) {
            // wait until every wg's plane-`wave` producer published h_{t-1}
            while (true) {
                int v = __hip_atomic_load(&flagp[lane & (NWG - 1)],
                                          __ATOMIC_RELAXED,
                                          __HIP_MEMORY_SCOPE_AGENT);
                if (__all(v >= t)) break;
                __builtin_amdgcn_s_sleep(1);
            }
            // cheap wg-scope fence: compiler barrier, no cache maintenance
            __builtin_amdgcn_fence(__ATOMIC_ACQUIRE, "workgroup");

            const char* hb = hb_base + (size_t)((t - 1) & 1) * 262144;

            u32x4 buf[PFD][2];
            #pragma unroll
            for (int d = 0; d < PFD; d++) {
                buf[d][0] = load_b128_agent(hb + d * 2048);
                buf[d][1] = load_b128_agent(hb + d * 2048 + 1024);
            }

            #pragma unroll
            for (int kc = 0; kc < 32; kc++) {
                if (kc < 24) {
                    asm volatile("s_waitcnt vmcnt(14)" ::: "memory");
                } else if (kc == 24) {
                    asm volatile("s_waitcnt vmcnt(0)" ::: "memory");
                }
                __builtin_amdgcn_sched_barrier(0);

                u32x4 c0 = buf[kc & (PFD - 1)][0];
                u32x4 c1 = buf[kc & (PFD - 1)][1];
                short8 ah, al;
                #pragma unroll
                for (int i = 0; i < 4; i++) {
                    ah[i]     = (short)(c0[i] >> 16);
                    al[i]     = (short)(c0[i] & 0xffffu);
                    ah[4 + i] = (short)(c1[i] >> 16);
                    al[4 + i] = (short)(c1[i] & 0xffffu);
                }
                short8 wh0 = whds[0][kc][lane];
                short8 wl0 = wlds[0][kc][lane];
                short8 wh1 = whds[1][kc][lane];
                short8 wl1 = wlds[1][kc][lane];
                acc[0][0] = __builtin_amdgcn_mfma_f32_16x16x32_bf16(ah, wh0, acc[0][0], 0, 0, 0);
                acc[0][1] = __builtin_amdgcn_mfma_f32_16x16x32_bf16(ah, wl0, acc[0][1], 0, 0, 0);
                acc[0][2] = __builtin_amdgcn_mfma_f32_16x16x32_bf16(al, wh0, acc[0][2], 0, 0, 0);
                acc[1][0] = __builtin_amdgcn_mfma_f32_16x16x32_bf16(ah, wh1, acc[1][0], 0, 0, 0);
                acc[1][1] = __builtin_amdgcn_mfma_f32_16x16x32_bf16(ah, wl1, acc[1][1], 0, 0, 0);
                acc[1][2] = __builtin_amdgcn_mfma_f32_16x16x32_bf16(al, wh1, acc[1][2], 0, 0, 0);

                if (kc + PFD < 32) {
                    buf[kc & (PFD - 1)][0] =
                        load_b128_agent(hb + (kc + PFD) * 2048);
                    buf[kc & (PFD - 1)][1] =
                        load_b128_agent(hb + (kc + PFD) * 2048 + 1024);
                }
            }
        }

        // epilogue: h = tanh(acc + xp); publish swizzled u32s, then flag
        float hv[2][4];
        #pragma unroll
        for (int g = 0; g < 2; g++)
            #pragma unroll
            for (int r = 0; r < 4; r++)
                hv[g][r] = tanhf(acc[g][0][r] + acc[g][1][r] + acc[g][2][r]
                                 + xv[g][r]);

        if (t + 1 < T_) {
            #pragma unroll
            for (int g = 0; g < 2; g++) {
                unsigned int* pb = pb_base[g] + (size_t)(t & 1) * 65536;
                #pragma unroll
                for (int r = 0; r < 4; r++) {
                    unsigned short hi = f2bf(hv[g][r]);
                    unsigned short lo = f2bf(hv[g][r] - bf2f(hi));
                    unsigned int pk = ((unsigned int)hi << 16)
                                    | (unsigned int)lo;
                    __hip_atomic_store(&pb[r * 4], pk, __ATOMIC_RELAXED,
                                       __HIP_MEMORY_SCOPE_AGENT);
                }
            }
            asm volatile("s_waitcnt vmcnt(0)" ::: "memory");
            if (lane == 0)
                __hip_atomic_store(&flagp[wg], t + 1, __ATOMIC_RELAXED,
                                   __HIP_MEMORY_SCOPE_AGENT);
        }

        // off critical path: fp32 h store to d_out (wg-private addresses)
        #pragma unroll
        for (int r = 0; r < 4; r++) {
            out[oidx[r]]      = hv[0][r];
            out[oidx[r] + 16] = hv[1][r];
            oidx[r] += H_;
            xv[0][r] = nxv[0][r];
            xv[1][r] = nxv[1][r];
        }
    }
}

// ---------------------------------------------------------------------------
extern "C" void kernel_launch(void* const* d_in, const int* in_sizes, int n_in,
                              void* d_out, int out_size, void* d_ws, size_t ws_size,
                              hipStream_t stream) {
    const float* x        = (const float*)d_in[0];  // [B,T,I]
    const float* hidden_w = (const float*)d_in[1];  // [H,H]
    const float* input_w  = (const float*)d_in[2];  // [I,H]
    const float* bias     = (const float*)d_in[3];  // [H]
    float* out = (float*)d_out;                     // [B,T,H]

    // ws layout: hbuf swizzled [2][4][32][2][64][4] u32 = 512 KiB, then flags
    unsigned int* hbuf = (unsigned int*)d_ws;
    int* flags = (int*)((char*)d_ws + (size_t)512 * 1024);

    hipMemsetAsync(flags, 0, 4 * NWG * sizeof(int), stream);

    dim3 pgrid(H_ / BN, (B_ * T_) / BM);   // (8, 512)
    proj_kernel<<<pgrid, 256, 0, stream>>>(x, input_w, bias, out);
    scan_kernel<<<NWG, 256, 0, stream>>>(hidden_w, out, hbuf, flags);
}